// Round 10
// baseline (64.640 us; speedup 1.0000x reference)
//
#include <hip/hip_runtime.h>

#define BSZ 64
#define LMAX 128
#define DIM 2048
#define NPOS (BSZ * LMAX)   // 8192
#define NPROJ_BLOCKS 1024   // 8 positions per block
#define NTAIL BSZ           // one loss block per batch

struct Ctrl {
    float accum;            // loss sum
    int   count;            // valid-pair count
    int   done2;            // finished loss-blocks
    int   pad[13];
    int   done[BSZ * 16];   // per-batch proj-block counters, 64 B apart
};

// ---------------- kernel 0: init (1 block; first node, stream-ordered) ------
__global__ void init_kernel(Ctrl* __restrict__ ctrl) {
    int* p = (int*)ctrl;
    const int n = sizeof(Ctrl) / 4;
    for (int i = threadIdx.x; i < n; i += 256) p[i] = 0;
}

// ---------------- kernel 1: fused proj + per-batch tail loss ----------------
// Blocks 0..1023: proj (round-9 structure: 8 waves = 2 wave-quads x 4
// positions; quarter-row W-slices in registers; 6-shuffle reduction).
// Blocks 1024..1087: tail block for batch b — tid0 spins until b's 16 proj
// blocks ticked (release fence by writer tid0, acquire fence by reader tid0
// ONLY — round 5's mistake was 512-thread fences), then 512-thread loss.
__global__ __launch_bounds__(512, 6) void fused_kernel(
        const float* __restrict__ enc,
        const float* __restrict__ W,
        const int* __restrict__ mask,
        const float* __restrict__ bias,
        float* __restrict__ proj,      // [4][NPOS][4] floats
        Ctrl* __restrict__ ctrl,
        float* __restrict__ out) {
    const int tid = threadIdx.x;

    if (blockIdx.x < NPROJ_BLOCKS) {
        // ================= proj phase =================
        const int wid  = tid >> 6;
        const int lane = tid & 63;
        const int quad = wid >> 2;                      // 0..1
        const int qw   = wid & 3;                       // quarter 0..3
        const int p0   = (blockIdx.x * 2 + quad) * 4;   // first of 4 positions

        const float4* __restrict__ W4 = (const float4*)W;
        float4 wl0[2], wl1[2], wr0[2], wr1[2];
        #pragma unroll
        for (int it = 0; it < 2; ++it) {
            const int idx = qw * 128 + it * 64 + lane;
            wl0[it] = W4[idx * 2];
            wl1[it] = W4[idx * 2 + 1];
            wr0[it] = W4[1024 + idx * 2];
            wr1[it] = W4[1024 + idx * 2 + 1];
        }

        const float4* __restrict__ h4 = (const float4*)enc;
        const size_t base = (size_t)p0 * (DIM / 4) + qw * 128 + lane;

        float4 hA0 = h4[base];
        float4 hA1 = h4[base + 64];

        float* __restrict__ projf = proj + (size_t)qw * NPOS * 4;

        #pragma unroll
        for (int q = 0; q < 4; ++q) {
            float4 hB0, hB1;
            if (q < 3) {
                const size_t nb = base + (size_t)(q + 1) * (DIM / 4);
                hB0 = h4[nb];
                hB1 = h4[nb + 64];
            }
            float a0, a1, a2, a3;
            a0 = hA0.x * wl0[0].x + hA0.y * wl0[0].z + hA0.z * wl1[0].x + hA0.w * wl1[0].z
               + hA1.x * wl0[1].x + hA1.y * wl0[1].z + hA1.z * wl1[1].x + hA1.w * wl1[1].z;
            a1 = hA0.x * wl0[0].y + hA0.y * wl0[0].w + hA0.z * wl1[0].y + hA0.w * wl1[0].w
               + hA1.x * wl0[1].y + hA1.y * wl0[1].w + hA1.z * wl1[1].y + hA1.w * wl1[1].w;
            a2 = hA0.x * wr0[0].x + hA0.y * wr0[0].z + hA0.z * wr1[0].x + hA0.w * wr1[0].z
               + hA1.x * wr0[1].x + hA1.y * wr0[1].z + hA1.z * wr1[1].x + hA1.w * wr1[1].z;
            a3 = hA0.x * wr0[0].y + hA0.y * wr0[0].w + hA0.z * wr1[0].y + hA0.w * wr1[0].w
               + hA1.x * wr0[1].y + hA1.y * wr0[1].w + hA1.z * wr1[1].y + hA1.w * wr1[1].w;

            const bool o1 = (lane & 1);
            const float r1 = __shfl_xor(o1 ? a0 : a1, 1);
            float s = (o1 ? a1 : a0) + r1;
            const float r2 = __shfl_xor(o1 ? a2 : a3, 1);
            float t = (o1 ? a3 : a2) + r2;
            const bool o2 = (lane & 2);
            const float r3 = __shfl_xor(o2 ? s : t, 2);
            float u = (o2 ? t : s) + r3;
            u += __shfl_xor(u, 4);
            u += __shfl_xor(u, 8);
            u += __shfl_xor(u, 16);
            u += __shfl_xor(u, 32);
            if (lane < 4) projf[(size_t)(p0 + q) * 4 + lane] = u;

            if (q < 3) { hA0 = hB0; hA1 = hB1; }
        }

        // release: all block stores drained by syncthreads' vmcnt(0),
        // then ONE agent-scope fence + per-batch ticket
        __syncthreads();
        if (tid == 0) {
            __threadfence();
            atomicAdd(&ctrl->done[(blockIdx.x >> 4) * 16], 1);
        }
        return;
    }

    // ================= tail loss phase (one block per batch) =================
    __shared__ float4 s_proj[LMAX];
    __shared__ float  s_w[8];
    __shared__ int    s_m[8];

    const int b    = blockIdx.x - NPROJ_BLOCKS;
    const int lane = tid & 63;

    if (tid == 0) {
        while (atomicAdd(&ctrl->done[b * 16], 0) < 16)
            __builtin_amdgcn_s_sleep(1);
        __threadfence();   // acquire: inv L1/L2 before reading proj
    }
    __syncthreads();

    const float4* proj4 = (const float4*)proj;
    if (tid < LMAX) {
        const float4 pa = proj4[0 * NPOS + b * LMAX + tid];
        const float4 pb = proj4[1 * NPOS + b * LMAX + tid];
        const float4 pc = proj4[2 * NPOS + b * LMAX + tid];
        const float4 pd = proj4[3 * NPOS + b * LMAX + tid];
        float4 v;
        v.x = (pa.x + pb.x) + (pc.x + pd.x);
        v.y = (pa.y + pb.y) + (pc.y + pd.y);
        v.z = (pa.z + pb.z) + (pc.z + pd.z);
        v.w = (pa.w + pb.w) + (pc.w + pd.w);
        s_proj[tid] = v;
    }

    int m = (tid < LMAX) ? mask[b * LMAX + tid] : 0;
    #pragma unroll
    for (int off = 32; off >= 1; off >>= 1) m += __shfl_xor(m, off);
    if (lane == 0) s_m[tid >> 6] = m;
    __syncthreads();

    int T = 0;
    #pragma unroll
    for (int w = 0; w < 8; ++w) T += s_m[w];
    const float b0 = bias[0];
    const float b1 = bias[1];

    float local = 0.f;
    const int tmax = T << 7;
    for (int t = tid; t < tmax; t += 512) {
        const int j = t >> 7;
        const int k = t & (LMAX - 1);
        if (k < j) {
            const float4 pj = s_proj[j];
            const float4 pk = s_proj[k];
            const float l0 = pj.x + pk.z + b0;
            const float l1 = pj.y + pk.w + b1;
            const bool  pos = (k == j - 1);
            const float d  = pos ? (l0 - l1) : (l1 - l0);
            local += fmaxf(d, 0.f) + __logf(1.f + __expf(-fabsf(d)));
        }
    }

    #pragma unroll
    for (int off = 32; off >= 1; off >>= 1) local += __shfl_xor(local, off);
    if (lane == 0) s_w[tid >> 6] = local;
    __syncthreads();

    if (tid == 0) {
        float s = 0.f;
        #pragma unroll
        for (int w = 0; w < 8; ++w) s += s_w[w];
        atomicAdd(&ctrl->accum, s);
        atomicAdd(&ctrl->count, T * (T - 1) / 2);
        __threadfence();
        const int prev = atomicAdd(&ctrl->done2, 1);
        if (prev == NTAIL - 1) {
            const float sum = atomicAdd(&ctrl->accum, 0.0f);
            const int   c   = atomicAdd(&ctrl->count, 0);
            out[0] = sum / (float)(c > 1 ? c : 1);
        }
    }
}

extern "C" void kernel_launch(void* const* d_in, const int* in_sizes, int n_in,
                              void* d_out, int out_size, void* d_ws, size_t ws_size,
                              hipStream_t stream) {
    const float* enc  = (const float*)d_in[0];  // [BSZ, LMAX, DIM] fp32
    const int*   mask = (const int*)d_in[1];    // [BSZ, LMAX] int32
    const float* W    = (const float*)d_in[2];  // [2*DIM, 2] fp32
    const float* bias = (const float*)d_in[3];  // [2] fp32
    float* out = (float*)d_out;

    float* proj = (float*)d_ws;                          // 4*NPOS float4 = 512 KB
    Ctrl*  ctrl = (Ctrl*)((char*)d_ws + 4 * NPOS * 16);

    init_kernel<<<1, 256, 0, stream>>>(ctrl);
    fused_kernel<<<NPROJ_BLOCKS + NTAIL, 512, 0, stream>>>(
        enc, W, mask, bias, proj, ctrl, out);
}

// Round 11
// 30.034 us; speedup vs baseline: 2.1522x; 2.1522x over previous
//
#include <hip/hip_runtime.h>

#define BSZ 64
#define LMAX 128
#define DIM 2048

struct Ctrl {
    float accum;   // loss sum
    int   count;   // valid-pair count
    int   done2;   // finished blocks
};

// ---------------- mono kernel: one self-contained block per batch ----------
// 64 blocks x 1024 threads (16 waves). Waves split as 4 position-groups x 4
// dim-quarters: wave (g,qw) computes quarter-row partial dots for positions
// g*32..g*32+31 with its W-slice in registers (8 float4 = 32 VGPR), writes
// partials to LDS; after one __syncthreads the same block runs that batch's
// pairwise loss from LDS. No cross-block dependencies at all.
__global__ __launch_bounds__(1024) void mono_kernel(
        const float* __restrict__ enc,
        const float* __restrict__ W,
        const int* __restrict__ mask,
        const float* __restrict__ bias,
        Ctrl* __restrict__ ctrl,
        float* __restrict__ out) {
    __shared__ float  s_part[4][LMAX][4];   // [quarter][pos][component] 8 KB
    __shared__ float4 s_proj[LMAX];         // combined projections     2 KB
    __shared__ float  s_w[16];
    __shared__ int    s_m[2];

    const int b    = blockIdx.x;
    const int tid  = threadIdx.x;
    const int wid  = tid >> 6;
    const int lane = tid & 63;
    const int g    = wid >> 2;              // position group 0..3
    const int qw   = wid & 3;               // dim quarter  0..3

    // ---- W quarter-slice into registers ----
    const float4* __restrict__ W4 = (const float4*)W;   // [2*DIM,2] row-major
    float4 wl0[2], wl1[2], wr0[2], wr1[2];
    #pragma unroll
    for (int it = 0; it < 2; ++it) {
        const int idx = qw * 128 + it * 64 + lane;
        wl0[it] = W4[idx * 2];
        wl1[it] = W4[idx * 2 + 1];
        wr0[it] = W4[1024 + idx * 2];
        wr1[it] = W4[1024 + idx * 2 + 1];
    }

    // ---- turn length (waves 0-1 only), before the heavy loop ----
    if (tid < LMAX) {
        int m = mask[b * LMAX + tid];
        #pragma unroll
        for (int off = 32; off >= 1; off >>= 1) m += __shfl_xor(m, off);
        if (lane == 0) s_m[wid] = m;
    }

    // ---- proj: 32 positions per wave, quarter-row each ----
    const float4* __restrict__ h4 = (const float4*)enc;
    const int    pl0  = g * 32;                                   // local pos base
    const size_t base = ((size_t)(b * LMAX + pl0)) * (DIM / 4) + qw * 128 + lane;

    float4 hA0 = h4[base];
    float4 hA1 = h4[base + 64];

    for (int q = 0; q < 32; ++q) {
        float4 hB0, hB1;
        if (q < 31) {
            const size_t nb = base + (size_t)(q + 1) * (DIM / 4);
            hB0 = h4[nb];
            hB1 = h4[nb + 64];
        }
        float a0, a1, a2, a3;
        a0 = hA0.x * wl0[0].x + hA0.y * wl0[0].z + hA0.z * wl1[0].x + hA0.w * wl1[0].z
           + hA1.x * wl0[1].x + hA1.y * wl0[1].z + hA1.z * wl1[1].x + hA1.w * wl1[1].z;
        a1 = hA0.x * wl0[0].y + hA0.y * wl0[0].w + hA0.z * wl1[0].y + hA0.w * wl1[0].w
           + hA1.x * wl0[1].y + hA1.y * wl0[1].w + hA1.z * wl1[1].y + hA1.w * wl1[1].w;
        a2 = hA0.x * wr0[0].x + hA0.y * wr0[0].z + hA0.z * wr1[0].x + hA0.w * wr1[0].z
           + hA1.x * wr0[1].x + hA1.y * wr0[1].z + hA1.z * wr1[1].x + hA1.w * wr1[1].z;
        a3 = hA0.x * wr0[0].y + hA0.y * wr0[0].w + hA0.z * wr1[0].y + hA0.w * wr1[0].w
           + hA1.x * wr0[1].y + hA1.y * wr0[1].w + hA1.z * wr1[1].y + hA1.w * wr1[1].w;

        // fold 4 accs to residue lane&3 (3 shfl), then 4-step butterfly
        const bool o1 = (lane & 1);
        const float r1 = __shfl_xor(o1 ? a0 : a1, 1);
        float s = (o1 ? a1 : a0) + r1;
        const float r2 = __shfl_xor(o1 ? a2 : a3, 1);
        float t = (o1 ? a3 : a2) + r2;
        const bool o2 = (lane & 2);
        const float r3 = __shfl_xor(o2 ? s : t, 2);
        float u = (o2 ? t : s) + r3;
        u += __shfl_xor(u, 4);
        u += __shfl_xor(u, 8);
        u += __shfl_xor(u, 16);
        u += __shfl_xor(u, 32);
        if (lane < 4) s_part[qw][pl0 + q][lane] = u;

        if (q < 31) { hA0 = hB0; hA1 = hB1; }
    }
    __syncthreads();

    // ---- combine quarters into s_proj ----
    if (tid < LMAX) {
        float4 v;
        const float4 p0 = *(const float4*)s_part[0][tid];
        const float4 p1 = *(const float4*)s_part[1][tid];
        const float4 p2 = *(const float4*)s_part[2][tid];
        const float4 p3 = *(const float4*)s_part[3][tid];
        v.x = (p0.x + p1.x) + (p2.x + p3.x);
        v.y = (p0.y + p1.y) + (p2.y + p3.y);
        v.z = (p0.z + p1.z) + (p2.z + p3.z);
        v.w = (p0.w + p1.w) + (p2.w + p3.w);
        s_proj[tid] = v;
    }
    __syncthreads();

    // ---- pairwise NLL over this batch ----
    const int   T  = s_m[0] + s_m[1];
    const float b0 = bias[0];
    const float b1 = bias[1];

    float local = 0.f;
    const int tmax = T << 7;
    for (int t = tid; t < tmax; t += 1024) {
        const int j = t >> 7;
        const int k = t & (LMAX - 1);
        if (k < j) {
            const float4 pj = s_proj[j];
            const float4 pk = s_proj[k];
            const float l0 = pj.x + pk.z + b0;
            const float l1 = pj.y + pk.w + b1;
            const bool  pos = (k == j - 1);
            const float d  = pos ? (l0 - l1) : (l1 - l0);
            local += fmaxf(d, 0.f) + __logf(1.f + __expf(-fabsf(d)));
        }
    }
    #pragma unroll
    for (int off = 32; off >= 1; off >>= 1) local += __shfl_xor(local, off);
    if (lane == 0) s_w[wid] = local;
    __syncthreads();

    if (tid == 0) {
        float s = 0.f;
        #pragma unroll
        for (int w = 0; w < 16; ++w) s += s_w[w];
        atomicAdd(&ctrl->accum, s);
        atomicAdd(&ctrl->count, T * (T - 1) / 2);
        __threadfence();
        const int prev = atomicAdd(&ctrl->done2, 1);
        if (prev == BSZ - 1) {
            const float sum = atomicAdd(&ctrl->accum, 0.0f);
            const int   c   = atomicAdd(&ctrl->count, 0);
            out[0] = sum / (float)(c > 1 ? c : 1);
        }
    }
}

extern "C" void kernel_launch(void* const* d_in, const int* in_sizes, int n_in,
                              void* d_out, int out_size, void* d_ws, size_t ws_size,
                              hipStream_t stream) {
    const float* enc  = (const float*)d_in[0];  // [BSZ, LMAX, DIM] fp32
    const int*   mask = (const int*)d_in[1];    // [BSZ, LMAX] int32
    const float* W    = (const float*)d_in[2];  // [2*DIM, 2] fp32
    const float* bias = (const float*)d_in[3];  // [2] fp32
    float* out = (float*)d_out;

    Ctrl* ctrl = (Ctrl*)d_ws;

    hipMemsetAsync(ctrl, 0, sizeof(Ctrl), stream);   // 12 B, graph-legal
    mono_kernel<<<BSZ, 1024, 0, stream>>>(enc, W, mask, bias, ctrl, out);
}

// Round 12
// 27.948 us; speedup vs baseline: 2.3129x; 1.0746x over previous
//
#include <hip/hip_runtime.h>

#define BSZ 64
#define LMAX 128
#define DIM 2048
#define NPOS (BSZ * LMAX)   // 8192

struct Ctrl {
    float accum;   // loss sum
    int   count;   // valid-pair count
    int   done2;   // finished loss-blocks
};

// ---------------- kernel 1: projections (+ ctrl init) ----------------
// 1024 blocks x 512 threads = 8 waves. Wave e takes the e-th EIGHTH of the
// row (256 dims = 1 float4-chunk per lane): W slice = 4 float4 (16 VGPR,
// too cheap for the compiler to rematerialize), and ALL 8 positions' h
// chunks (8 float4 = 8 KB/wave) are issued back-to-back -> structural
// depth-8 memory-level parallelism. Accumulators reused per position.
// Eight partial buffers; loss sums them.
__global__ __launch_bounds__(512, 4) void proj_kernel(
        const float* __restrict__ enc,
        const float* __restrict__ W,
        float* __restrict__ proj,      // [8][NPOS][4] floats
        Ctrl* __restrict__ ctrl) {
    if (blockIdx.x == 0 && threadIdx.x == 0) {
        ctrl->accum = 0.f; ctrl->count = 0; ctrl->done2 = 0;
    }

    const int tid  = threadIdx.x;
    const int e    = tid >> 6;          // eighth 0..7
    const int lane = tid & 63;
    const int p0   = blockIdx.x * 8;    // first of 8 positions
    const int idx  = e * 64 + lane;     // chunk index 0..511

    // ---- W eighth-slice: 4 float4 = 16 VGPR ----
    const float4* __restrict__ W4 = (const float4*)W;   // [2*DIM,2] row-major
    const float4 wl0 = W4[idx * 2];
    const float4 wl1 = W4[idx * 2 + 1];
    const float4 wr0 = W4[1024 + idx * 2];
    const float4 wr1 = W4[1024 + idx * 2 + 1];

    // ---- all 8 h chunks issued up front ----
    const float4* __restrict__ h4 = (const float4*)enc;
    const size_t base = (size_t)p0 * (DIM / 4) + idx;
    float4 h[8];
    #pragma unroll
    for (int p = 0; p < 8; ++p) h[p] = h4[base + (size_t)p * (DIM / 4)];

    float* __restrict__ projf = proj + (size_t)e * NPOS * 4;

    #pragma unroll
    for (int p = 0; p < 8; ++p) {
        const float4 hp = h[p];
        float a0 = hp.x * wl0.x + hp.y * wl0.z + hp.z * wl1.x + hp.w * wl1.z;
        float a1 = hp.x * wl0.y + hp.y * wl0.w + hp.z * wl1.y + hp.w * wl1.w;
        float a2 = hp.x * wr0.x + hp.y * wr0.z + hp.z * wr1.x + hp.w * wr1.z;
        float a3 = hp.x * wr0.y + hp.y * wr0.w + hp.z * wr1.y + hp.w * wr1.w;

        // fold 4 accs to residue lane&3 (3 shfl), then 4-step butterfly
        const bool o1 = (lane & 1);
        const float r1 = __shfl_xor(o1 ? a0 : a1, 1);
        float s = (o1 ? a1 : a0) + r1;
        const float r2 = __shfl_xor(o1 ? a2 : a3, 1);
        float t = (o1 ? a3 : a2) + r2;
        const bool o2 = (lane & 2);
        const float r3 = __shfl_xor(o2 ? s : t, 2);
        float u = (o2 ? t : s) + r3;
        u += __shfl_xor(u, 4);
        u += __shfl_xor(u, 8);
        u += __shfl_xor(u, 16);
        u += __shfl_xor(u, 32);
        if (lane < 4) projf[(size_t)(p0 + p) * 4 + lane] = u;
    }
}

// ---------------- kernel 2: pairwise NLL + finalize ----------------
// 256 blocks x 256 threads; 4 blocks per batch; sums the eight proj eighths.
__global__ __launch_bounds__(256) void loss_kernel(
        const int* __restrict__ mask,
        const float* __restrict__ proj,
        const float* __restrict__ bias,
        Ctrl* __restrict__ ctrl,
        float* __restrict__ out) {
    __shared__ float4 s_proj[LMAX];
    __shared__ float  s_w[4];
    __shared__ int    s_m[4];

    const int b   = blockIdx.x >> 2;
    const int q   = blockIdx.x & 3;
    const int tid = threadIdx.x;

    const float4* proj4 = (const float4*)proj;
    if (tid < LMAX) {
        float x = 0.f, y = 0.f, z = 0.f, w = 0.f;
        #pragma unroll
        for (int e = 0; e < 8; ++e) {
            const float4 pe = proj4[e * NPOS + b * LMAX + tid];
            x += pe.x; y += pe.y; z += pe.z; w += pe.w;
        }
        float4 v; v.x = x; v.y = y; v.z = z; v.w = w;
        s_proj[tid] = v;
    }

    int m = (tid < LMAX) ? mask[b * LMAX + tid] : 0;
    #pragma unroll
    for (int off = 32; off >= 1; off >>= 1) m += __shfl_xor(m, off);
    if ((tid & 63) == 0) s_m[tid >> 6] = m;
    __syncthreads();

    const int   T  = s_m[0] + s_m[1] + s_m[2] + s_m[3];
    const float b0 = bias[0];
    const float b1 = bias[1];

    float local = 0.f;
    const int tmax = T << 7;
    for (int t = q * 256 + tid; t < tmax; t += 1024) {
        const int j = t >> 7;
        const int k = t & (LMAX - 1);
        if (k < j) {
            const float4 pj = s_proj[j];
            const float4 pk = s_proj[k];
            const float l0 = pj.x + pk.z + b0;
            const float l1 = pj.y + pk.w + b1;
            const bool  pos = (k == j - 1);
            const float d  = pos ? (l0 - l1) : (l1 - l0);
            local += fmaxf(d, 0.f) + __logf(1.f + __expf(-fabsf(d)));
        }
    }

    #pragma unroll
    for (int off = 32; off >= 1; off >>= 1) local += __shfl_xor(local, off);
    if ((tid & 63) == 0) s_w[tid >> 6] = local;
    __syncthreads();

    if (tid == 0) {
        atomicAdd(&ctrl->accum, s_w[0] + s_w[1] + s_w[2] + s_w[3]);
        if (q == 0) atomicAdd(&ctrl->count, T * (T - 1) / 2);
        __threadfence();
        const int prev = atomicAdd(&ctrl->done2, 1);
        if (prev == 4 * BSZ - 1) {
            const float s = atomicAdd(&ctrl->accum, 0.0f);
            const int   c = atomicAdd(&ctrl->count, 0);
            out[0] = s / (float)(c > 1 ? c : 1);
        }
    }
}

extern "C" void kernel_launch(void* const* d_in, const int* in_sizes, int n_in,
                              void* d_out, int out_size, void* d_ws, size_t ws_size,
                              hipStream_t stream) {
    const float* enc  = (const float*)d_in[0];  // [BSZ, LMAX, DIM] fp32
    const int*   mask = (const int*)d_in[1];    // [BSZ, LMAX] int32
    const float* W    = (const float*)d_in[2];  // [2*DIM, 2] fp32
    const float* bias = (const float*)d_in[3];  // [2] fp32
    float* out = (float*)d_out;

    float* proj = (float*)d_ws;                          // 8*NPOS float4 = 2 MB
    Ctrl*  ctrl = (Ctrl*)((char*)d_ws + 8 * NPOS * 16);

    proj_kernel<<<NPOS / 8, 512, 0, stream>>>(enc, W, proj, ctrl);
    loss_kernel<<<4 * BSZ, 256, 0, stream>>>(mask, proj, bias, ctrl, out);
}

// Round 13
// 24.932 us; speedup vs baseline: 2.5927x; 1.1210x over previous
//
#include <hip/hip_runtime.h>

#define BSZ 64
#define LMAX 128
#define DIM 2048
#define NPOS (BSZ * LMAX)   // 8192

struct Ctrl {
    float accum;   // loss sum
    int   count;   // valid-pair count
    int   done2;   // finished loss-blocks
};

// ---------------- kernel 1: projections (+ ctrl init), T-gated ----------------
// 1024 blocks x 512 threads = 8 waves = 2 wave-quads x 4 dim-quarters.
// Each wave first computes its batch's turn length T (2 ints/lane + 6 shfl,
// wave-redundant, no barrier), then loads/projects ONLY positions p < T.
// Mean T ~= 65/128 -> ~half the enc bytes are skipped entirely.
// Quarter-row W-slices in registers; 6-shuffle reduction; 4 partial buffers.
__global__ __launch_bounds__(512, 6) void proj_kernel(
        const float* __restrict__ enc,
        const float* __restrict__ W,
        const int* __restrict__ mask,
        float* __restrict__ proj,      // [4][NPOS][4] floats
        Ctrl* __restrict__ ctrl) {
    if (blockIdx.x == 0 && threadIdx.x == 0) {
        ctrl->accum = 0.f; ctrl->count = 0; ctrl->done2 = 0;
    }

    const int tid  = threadIdx.x;
    const int wid  = tid >> 6;
    const int lane = tid & 63;
    const int quad = wid >> 2;                      // 0..1
    const int qw   = wid & 3;                       // quarter 0..3
    const int p0   = (blockIdx.x * 2 + quad) * 4;   // first of 4 positions
    const int b    = blockIdx.x >> 4;               // batch (16 blocks/batch)

    // ---- per-wave turn length: T = sum(mask[b]) ----
    int m = mask[b * LMAX + lane] + mask[b * LMAX + 64 + lane];
    #pragma unroll
    for (int off = 32; off >= 1; off >>= 1) m += __shfl_xor(m, off);
    const int T = m;                                // uniform across wave

    const int pl   = p0 & (LMAX - 1);               // position within batch
    const int nact = min(max(T - pl, 0), 4);        // active positions of our 4
    if (nact == 0) return;                          // whole wave-quad unused

    // ---- W quarter-slice into registers (8 float4 = 32 VGPR) ----
    const float4* __restrict__ W4 = (const float4*)W;   // [2*DIM,2] row-major
    float4 wl0[2], wl1[2], wr0[2], wr1[2];
    #pragma unroll
    for (int it = 0; it < 2; ++it) {
        const int idx = qw * 128 + it * 64 + lane;
        wl0[it] = W4[idx * 2];
        wl1[it] = W4[idx * 2 + 1];
        wr0[it] = W4[1024 + idx * 2];
        wr1[it] = W4[1024 + idx * 2 + 1];
    }

    // ---- h loads for active positions, issued back-to-back ----
    const float4* __restrict__ h4 = (const float4*)enc;
    const size_t base = (size_t)p0 * (DIM / 4) + qw * 128 + lane;

    float4 h0[4], h1[4];
    #pragma unroll
    for (int q = 0; q < 4; ++q) {
        if (q < nact) {
            const size_t a = base + (size_t)q * (DIM / 4);
            h0[q] = h4[a];
            h1[q] = h4[a + 64];
        }
    }

    float* __restrict__ projf = proj + (size_t)qw * NPOS * 4;

    #pragma unroll
    for (int q = 0; q < 4; ++q) {
        if (q < nact) {
            const float4 hA0 = h0[q];
            const float4 hA1 = h1[q];
            float a0, a1, a2, a3;
            a0 = hA0.x * wl0[0].x + hA0.y * wl0[0].z + hA0.z * wl1[0].x + hA0.w * wl1[0].z
               + hA1.x * wl0[1].x + hA1.y * wl0[1].z + hA1.z * wl1[1].x + hA1.w * wl1[1].z;
            a1 = hA0.x * wl0[0].y + hA0.y * wl0[0].w + hA0.z * wl1[0].y + hA0.w * wl1[0].w
               + hA1.x * wl0[1].y + hA1.y * wl0[1].w + hA1.z * wl1[1].y + hA1.w * wl1[1].w;
            a2 = hA0.x * wr0[0].x + hA0.y * wr0[0].z + hA0.z * wr1[0].x + hA0.w * wr1[0].z
               + hA1.x * wr0[1].x + hA1.y * wr0[1].z + hA1.z * wr1[1].x + hA1.w * wr1[1].z;
            a3 = hA0.x * wr0[0].y + hA0.y * wr0[0].w + hA0.z * wr1[0].y + hA0.w * wr1[0].w
               + hA1.x * wr0[1].y + hA1.y * wr0[1].w + hA1.z * wr1[1].y + hA1.w * wr1[1].w;

            // fold 4 accs to residue lane&3 (3 shfl), then 4-step butterfly
            const bool o1 = (lane & 1);
            const float r1 = __shfl_xor(o1 ? a0 : a1, 1);
            float s = (o1 ? a1 : a0) + r1;
            const float r2 = __shfl_xor(o1 ? a2 : a3, 1);
            float t = (o1 ? a3 : a2) + r2;
            const bool o2 = (lane & 2);
            const float r3 = __shfl_xor(o2 ? s : t, 2);
            float u = (o2 ? t : s) + r3;
            u += __shfl_xor(u, 4);
            u += __shfl_xor(u, 8);
            u += __shfl_xor(u, 16);
            u += __shfl_xor(u, 32);
            if (lane < 4) projf[(size_t)(p0 + q) * 4 + lane] = u;
        }
    }
}

// ---------------- kernel 2: pairwise NLL + finalize ----------------
// 256 blocks x 256 threads; 4 blocks per batch; sums the four proj quarters.
// Only reads proj[p] for p < T, so skipped positions' garbage is never used.
__global__ __launch_bounds__(256) void loss_kernel(
        const int* __restrict__ mask,
        const float* __restrict__ proj,
        const float* __restrict__ bias,
        Ctrl* __restrict__ ctrl,
        float* __restrict__ out) {
    __shared__ float4 s_proj[LMAX];
    __shared__ float  s_w[4];
    __shared__ int    s_m[4];

    const int b   = blockIdx.x >> 2;
    const int q   = blockIdx.x & 3;
    const int tid = threadIdx.x;

    int m = (tid < LMAX) ? mask[b * LMAX + tid] : 0;
    #pragma unroll
    for (int off = 32; off >= 1; off >>= 1) m += __shfl_xor(m, off);
    if ((tid & 63) == 0) s_m[tid >> 6] = m;
    __syncthreads();

    const int T = s_m[0] + s_m[1] + s_m[2] + s_m[3];

    const float4* proj4 = (const float4*)proj;
    if (tid < T) {
        const float4 pa = proj4[0 * NPOS + b * LMAX + tid];
        const float4 pb = proj4[1 * NPOS + b * LMAX + tid];
        const float4 pc = proj4[2 * NPOS + b * LMAX + tid];
        const float4 pd = proj4[3 * NPOS + b * LMAX + tid];
        float4 v;
        v.x = (pa.x + pb.x) + (pc.x + pd.x);
        v.y = (pa.y + pb.y) + (pc.y + pd.y);
        v.z = (pa.z + pb.z) + (pc.z + pd.z);
        v.w = (pa.w + pb.w) + (pc.w + pd.w);
        s_proj[tid] = v;
    }
    __syncthreads();

    const float b0 = bias[0];
    const float b1 = bias[1];

    float local = 0.f;
    const int tmax = T << 7;
    for (int t = q * 256 + tid; t < tmax; t += 1024) {
        const int j = t >> 7;
        const int k = t & (LMAX - 1);
        if (k < j) {
            const float4 pj = s_proj[j];
            const float4 pk = s_proj[k];
            const float l0 = pj.x + pk.z + b0;
            const float l1 = pj.y + pk.w + b1;
            const bool  pos = (k == j - 1);
            const float d  = pos ? (l0 - l1) : (l1 - l0);
            local += fmaxf(d, 0.f) + __logf(1.f + __expf(-fabsf(d)));
        }
    }

    #pragma unroll
    for (int off = 32; off >= 1; off >>= 1) local += __shfl_xor(local, off);
    if ((tid & 63) == 0) s_w[tid >> 6] = local;
    __syncthreads();

    if (tid == 0) {
        atomicAdd(&ctrl->accum, s_w[0] + s_w[1] + s_w[2] + s_w[3]);
        if (q == 0) atomicAdd(&ctrl->count, T * (T - 1) / 2);
        __threadfence();
        const int prev = atomicAdd(&ctrl->done2, 1);
        if (prev == 4 * BSZ - 1) {
            const float s = atomicAdd(&ctrl->accum, 0.0f);
            const int   c = atomicAdd(&ctrl->count, 0);
            out[0] = s / (float)(c > 1 ? c : 1);
        }
    }
}

extern "C" void kernel_launch(void* const* d_in, const int* in_sizes, int n_in,
                              void* d_out, int out_size, void* d_ws, size_t ws_size,
                              hipStream_t stream) {
    const float* enc  = (const float*)d_in[0];  // [BSZ, LMAX, DIM] fp32
    const int*   mask = (const int*)d_in[1];    // [BSZ, LMAX] int32
    const float* W    = (const float*)d_in[2];  // [2*DIM, 2] fp32
    const float* bias = (const float*)d_in[3];  // [2] fp32
    float* out = (float*)d_out;

    float* proj = (float*)d_ws;                          // 4*NPOS float4 = 512 KB
    Ctrl*  ctrl = (Ctrl*)((char*)d_ws + 4 * NPOS * 16);

    proj_kernel<<<NPOS / 8, 512, 0, stream>>>(enc, W, mask, proj, ctrl);
    loss_kernel<<<4 * BSZ, 256, 0, stream>>>(mask, proj, bias, ctrl, out);
}